// Round 13
// baseline (457.244 us; speedup 1.0000x reference)
//
#include <hip/hip_runtime.h>
#include <cstdint>

// Problem constants (from reference)
constexpr int G = 4, N = 50000, E = 800000;
constexpr int FIN = 64, HID = 128, FOUT = 64;
constexpr int NB = (N + 1023) / 1024;  // scan blocks per graph = 49

// Radix CSR-build parameters (R9)
constexpr int PB = 64;               // partition blocks per graph
constexpr int CP = E / PB;           // 12500 edges per partition chunk (exact)
constexpr int NBK = (N + 255) / 256; // 196 dst-buckets of 256 nodes

// Fused layer-1 tiling (R16)
constexpr int NT = (N + 63) / 64;    // 782 row-tiles per graph
constexpr int NTH = 391;             // tiles per half-XCD pair (782/2)

typedef unsigned short ushort;
typedef _Float16 f16;
typedef _Float16 h8 __attribute__((ext_vector_type(8)));
typedef float f4 __attribute__((ext_vector_type(4)));

__device__ __forceinline__ ushort f2h(float f) {  // v_cvt_f16_f32 (RNE)
  f16 h = (f16)f;
  return __builtin_bit_cast(ushort, h);
}
__device__ __forceinline__ float h2f(ushort u) {  // v_cvt_f32_f16
  f16 h = __builtin_bit_cast(f16, u);
  return (float)h;
}

// XCD-confined swizzle: block b -> XCD (b&7), 2 XCDs per graph.
__device__ __forceinline__ void xcd_map(int b, int& g, int& chunk) {
  int xcd = b & 7;
  int sub = b >> 3;  // 0..6249
  g = xcd >> 1;
  chunk = (xcd & 1) * 6250 + sub;  // 0..12499
}

// ---------------- fp32 -> fp16 conversion of x, PRE-SCALED by dinv ----------------
__global__ void k_x2h(const float4* __restrict__ X, const float* __restrict__ dinv,
                      ushort4* __restrict__ Xh, int n4) {
  int i = blockIdx.x * blockDim.x + threadIdx.x;
  if (i >= n4) return;
  float sc = dinv[i >> 4];  // 16 float4 per 64-wide row
  float4 v = X[i];
  ushort4 o = {f2h(sc * v.x), f2h(sc * v.y), f2h(sc * v.z), f2h(sc * v.w)};
  Xh[i] = o;
}

// ---------------- W1/W2 -> fp16 MFMA fragments (R17) ----------------
// Fragment convention (consistent for A and B, so any k-grouping cancels):
// lane l holds {row|col} = l&15, k = (l>>4)*8 + j (j=0..7, contiguous 16B).
// W1f[g][nt(8)][kb(2)][lane(64)][8], W2f[g][nt(4)][kb(4)][lane(64)][8].
__global__ void k_wprep(const float* __restrict__ W1, const float* __restrict__ W2,
                        ushort* __restrict__ W1f, ushort* __restrict__ W2f) {
  int g = blockIdx.x;
  int l = threadIdx.x;  // 64 threads
  for (int nt = 0; nt < 8; ++nt)
    for (int kb = 0; kb < 2; ++kb)
      for (int j = 0; j < 8; ++j) {
        int k = kb * 32 + (l >> 4) * 8 + j;
        int n = nt * 16 + (l & 15);
        W1f[((((size_t)g * 8 + nt) * 2 + kb) * 64 + l) * 8 + j] =
            f2h(W1[((size_t)g * FIN + k) * HID + n]);
      }
  for (int nt = 0; nt < 4; ++nt)
    for (int kb = 0; kb < 4; ++kb)
      for (int j = 0; j < 8; ++j) {
        int k = kb * 32 + (l >> 4) * 8 + j;
        int n = nt * 16 + (l & 15);
        W2f[((((size_t)g * 4 + nt) * 4 + kb) * 64 + l) * 8 + j] =
            f2h(W2[((size_t)g * HID + k) * FOUT + n]);
      }
}

// ---------------- CSR build: two-pass radix partition by dst (R9) ----------------
__global__ __launch_bounds__(256) void k_phist(const int* __restrict__ ei,
                                               int* __restrict__ PH) {
  __shared__ int h[NBK];
  int pb = blockIdx.x, g = blockIdx.y;
  for (int i = threadIdx.x; i < NBK; i += 256) h[i] = 0;
  __syncthreads();
  const int4* dst4 = (const int4*)(ei + (size_t)g * 2 * E + E + (size_t)pb * CP);
  for (int i = threadIdx.x; i < CP / 4; i += 256) {
    int4 d = dst4[i];
    atomicAdd(&h[d.x >> 8], 1);
    atomicAdd(&h[d.y >> 8], 1);
    atomicAdd(&h[d.z >> 8], 1);
    atomicAdd(&h[d.w >> 8], 1);
  }
  __syncthreads();
  for (int i = threadIdx.x; i < NBK; i += 256)
    PH[((size_t)g * NBK + i) * PB + pb] = h[i];
}

__global__ void k_pscan(const int* __restrict__ PH, int* __restrict__ POFF,
                        int* __restrict__ BB) {
  int g = blockIdx.x, k = threadIdx.x;
  int tot = 0;
  if (k < NBK) {
#pragma unroll 8
    for (int pb = 0; pb < PB; ++pb) tot += PH[((size_t)g * NBK + k) * PB + pb];
  }
  __shared__ int sm[256];
  sm[k] = tot;
  __syncthreads();
  for (int off = 1; off < 256; off <<= 1) {
    int v = (k >= off) ? sm[k - off] : 0;
    __syncthreads();
    sm[k] += v;
    __syncthreads();
  }
  int excl = sm[k] - tot;
  if (k < NBK) {
    BB[g * (NBK + 1) + k] = excl;
    if (k == NBK - 1) BB[g * (NBK + 1) + NBK] = excl + tot;  // == E
    int run = excl;
#pragma unroll 8
    for (int pb = 0; pb < PB; ++pb) {
      POFF[((size_t)g * NBK + k) * PB + pb] = run;
      run += PH[((size_t)g * NBK + k) * PB + pb];
    }
  }
}

__global__ __launch_bounds__(256) void k_part(const int* __restrict__ ei,
                                              const int* __restrict__ POFF,
                                              unsigned* __restrict__ pairs) {
  __shared__ int off[NBK];
  __shared__ int rk[NBK];
  int pb = blockIdx.x, g = blockIdx.y;
  for (int i = threadIdx.x; i < NBK; i += 256) {
    off[i] = POFF[((size_t)g * NBK + i) * PB + pb];
    rk[i] = 0;
  }
  __syncthreads();
  const int* base = ei + (size_t)g * 2 * E + (size_t)pb * CP;
  const int4* s4 = (const int4*)base;
  const int4* d4 = (const int4*)(base + E);
  unsigned* pg = pairs + (size_t)g * E;
  for (int i = threadIdx.x; i < CP / 4; i += 256) {
    int4 s = s4[i], d = d4[i];
    int sv[4] = {s.x, s.y, s.z, s.w};
    int dv[4] = {d.x, d.y, d.z, d.w};
#pragma unroll
    for (int k = 0; k < 4; ++k) {
      int b = dv[k] >> 8;
      int r = atomicAdd(&rk[b], 1);
      pg[off[b] + r] = (unsigned)sv[k] | ((unsigned)(dv[k] & 255) << 16);
    }
  }
}

__global__ __launch_bounds__(256) void k_bcnt(const unsigned* __restrict__ pairs,
                                              const int* __restrict__ BB,
                                              int* __restrict__ cnt) {
  __shared__ int h[256];
  int k = blockIdx.x, g = blockIdx.y;
  h[threadIdx.x] = 0;
  __syncthreads();
  int lo = BB[g * (NBK + 1) + k], hi = BB[g * (NBK + 1) + k + 1];
  const unsigned* pg = pairs + (size_t)g * E;
  for (int i = lo + (int)threadIdx.x; i < hi; i += 256)
    atomicAdd(&h[(pg[i] >> 16) & 255], 1);
  __syncthreads();
  int n0 = k << 8;
  int nn = min(256, N - n0);
  if ((int)threadIdx.x < nn) cnt[g * N + n0 + threadIdx.x] = h[threadIdx.x];
}

__global__ __launch_bounds__(256) void k_place(const unsigned* __restrict__ pairs,
                                               const int* __restrict__ BB,
                                               const int* __restrict__ rowptr,
                                               int* __restrict__ col) {
  __shared__ int rp[256];
  __shared__ int rk[256];
  int k = blockIdx.x, g = blockIdx.y;
  int n0 = k << 8;
  int nn = min(256, N - n0);
  if ((int)threadIdx.x < nn) rp[threadIdx.x] = rowptr[g * (N + 1) + n0 + threadIdx.x];
  rk[threadIdx.x] = 0;
  __syncthreads();
  int lo = BB[g * (NBK + 1) + k], hi = BB[g * (NBK + 1) + k + 1];
  const unsigned* pg = pairs + (size_t)g * E;
  int* cg = col + (size_t)g * E;
  for (int i = lo + (int)threadIdx.x; i < hi; i += 256) {
    unsigned p = pg[i];
    int dl = (p >> 16) & 255;
    int r = atomicAdd(&rk[dl], 1);
    cg[rp[dl] + r] = (int)(p & 0xffffu);
  }
}

// ---- 3-kernel exclusive scan of cnt -> rowptr (per graph) ----
__global__ void k_scan_partial(const int* __restrict__ cnt, int* __restrict__ part) {
  int g = blockIdx.y, b = blockIdx.x, tid = threadIdx.x;
  int base = b * 1024 + tid * 4;
  int s = 0;
#pragma unroll
  for (int k = 0; k < 4; ++k) {
    int i = base + k;
    if (i < N) s += cnt[g * N + i];
  }
  __shared__ int sm[256];
  sm[tid] = s;
  __syncthreads();
  for (int off = 128; off > 0; off >>= 1) {
    if (tid < off) sm[tid] += sm[tid + off];
    __syncthreads();
  }
  if (tid == 0) part[g * NB + b] = sm[0];
}

__global__ void k_scan_mid(int* __restrict__ part, int* __restrict__ rowptr) {
  int g = blockIdx.x;
  if (threadIdx.x != 0) return;
  int run = 0;
  for (int b = 0; b < NB; ++b) {
    int t = part[g * NB + b];
    part[g * NB + b] = run;
    run += t;
  }
  rowptr[g * (N + 1) + N] = run;  // == E
}

__global__ void k_scan_final(const int* __restrict__ cnt, const int* __restrict__ part,
                             int* __restrict__ rowptr, float* __restrict__ dinv) {
  int g = blockIdx.y, b = blockIdx.x, tid = threadIdx.x;
  int base = b * 1024 + tid * 4;
  int c[4];
  int s = 0;
#pragma unroll
  for (int k = 0; k < 4; ++k) {
    int i = base + k;
    c[k] = (i < N) ? cnt[g * N + i] : 0;
    s += c[k];
  }
  __shared__ int sm[256];
  sm[tid] = s;
  __syncthreads();
  for (int off = 1; off < 256; off <<= 1) {
    int v = (tid >= off) ? sm[tid - off] : 0;
    __syncthreads();
    sm[tid] += v;
    __syncthreads();
  }
  int excl = sm[tid] - s + part[g * NB + b];
#pragma unroll
  for (int k = 0; k < 4; ++k) {
    int i = base + k;
    if (i < N) {
      rowptr[g * (N + 1) + i] = excl;
      dinv[g * N + i] = rsqrtf((float)(c[k] + 1));  // +1 self loop
    }
    excl += c[k];
  }
}

// ---------------- aggregate core (R12) ----------------
__device__ __forceinline__ float agg_row(const ushort* __restrict__ hb,
                                         const int* __restrict__ cl, int rs, int re,
                                         int lane, float acc) {
  int j = rs;
  for (; j + 16 <= re; j += 16) {
    int s[16];
#pragma unroll
    for (int k = 0; k < 16; ++k) s[k] = cl[j + k];  // uniform -> s_load x16
    float v[16];
#pragma unroll
    for (int k = 0; k < 16; ++k) v[k] = h2f(hb[(size_t)s[k] * 64 + lane]);
#pragma unroll
    for (int k = 0; k < 16; ++k) acc += v[k];
  }
  for (; j + 8 <= re; j += 8) {
    int s[8];
#pragma unroll
    for (int k = 0; k < 8; ++k) s[k] = cl[j + k];
    float v[8];
#pragma unroll
    for (int k = 0; k < 8; ++k) v[k] = h2f(hb[(size_t)s[k] * 64 + lane]);
#pragma unroll
    for (int k = 0; k < 8; ++k) acc += v[k];
  }
  for (; j < re; ++j) acc += h2f(hb[(size_t)cl[j] * 64 + lane]);
  return acc;
}

// ---------------- fused layer 1: agg_in + MFMA MLP (R17) ----------------
// R16 post-mortem: VALU MLP (~8192 FMA-cyc/wave) kept k_l1 at 175us, 2x the
// ~89us gather floor. R17: gemm1/gemm2 on matrix cores (32 MFMA/wave ~ 160cyc).
// Fragment k-grouping is chosen consistently for A and B (k-perm cancels in
// the dot product); M/N lane mappings = l&15 (standard); C/D mapping is the
// m89-verified col=lane&15, row=(lane>>4)*4+reg. W fragments precomputed by
// k_wprep -> per-lane contiguous 16B global loads (L2-hot, no LDS). z (fp16,
// [64][72]) and h1 (fp16, [64][136]) share one 17.4KB LDS buffer; strides are
// 16B-aligned and at worst 2-way bank-aliased (free).
__global__ __launch_bounds__(256) void k_l1(const ushort* __restrict__ Xh,
                                            const int* __restrict__ rowptr,
                                            const int* __restrict__ col,
                                            const float* __restrict__ dinv,
                                            const ushort* __restrict__ W1f,
                                            const float* __restrict__ b1,
                                            const ushort* __restrict__ W2f,
                                            ushort* __restrict__ H2s) {
  constexpr int PZ = 72;    // z halfword stride (144B rows, 16B aligned)
  constexpr int PH1 = 136;  // h1 halfword stride (272B rows, 16B aligned)
  __shared__ alignas(16) ushort sm[64 * PH1];  // 17408B union: z, then h1
  int b = blockIdx.x;
  int xcd = b & 7;
  int sub = b >> 3;
  int g = xcd >> 1;
  int tile = (xcd & 1) * NTH + sub;  // 0..NT-1
  int R0 = tile * 64;
  int wv = threadIdx.x >> 6;
  int lane = threadIdx.x & 63;
  int l4 = lane >> 4, l15 = lane & 15;
  const ushort* hb = Xh + (size_t)g * N * FIN;
  const int* cl = col + (size_t)g * E;
  // phase 1: each wave aggregates 16 dst rows (lane = feature) -> z fp16 in LDS
  for (int i = 0; i < 16; ++i) {
    int d = __builtin_amdgcn_readfirstlane(R0 + wv * 16 + i);
    float zv = 0.f;
    if (d < N) {
      int rs = rowptr[g * (N + 1) + d];
      int re = rowptr[g * (N + 1) + d + 1];
      float acc = h2f(hb[(size_t)d * FIN + lane]);  // self loop (pre-scaled)
      acc = agg_row(hb, cl, rs, re, lane, acc);
      zv = dinv[g * N + d] * acc;
    }
    sm[(wv * 16 + i) * PZ + lane] = f2h(zv);
  }
  __syncthreads();
  // phase 2: gemm1 via MFMA. wave wv -> HID n-tiles {2wv, 2wv+1}.
  f4 acc1[4][2];
#pragma unroll
  for (int m = 0; m < 4; ++m)
#pragma unroll
    for (int nn = 0; nn < 2; ++nn) acc1[m][nn] = (f4){0.f, 0.f, 0.f, 0.f};
  h8 bf1[2][2];
#pragma unroll
  for (int nn = 0; nn < 2; ++nn)
#pragma unroll
    for (int kb = 0; kb < 2; ++kb)
      bf1[nn][kb] = *(const h8*)&W1f[((((size_t)g * 8 + (2 * wv + nn)) * 2 + kb) * 64 + lane) * 8];
#pragma unroll
  for (int m = 0; m < 4; ++m) {
#pragma unroll
    for (int kb = 0; kb < 2; ++kb) {
      h8 af = *(const h8*)&sm[(m * 16 + l15) * PZ + kb * 32 + l4 * 8];
#pragma unroll
      for (int nn = 0; nn < 2; ++nn)
        acc1[m][nn] = __builtin_amdgcn_mfma_f32_16x16x32_f16(af, bf1[nn][kb],
                                                             acc1[m][nn], 0, 0, 0);
    }
  }
  // bias + ELU (col = (2wv+nn)*16 + l15, same for all regs of a tile)
  float bv[2];
#pragma unroll
  for (int nn = 0; nn < 2; ++nn) bv[nn] = b1[g * HID + (2 * wv + nn) * 16 + l15];
#pragma unroll
  for (int m = 0; m < 4; ++m)
#pragma unroll
    for (int nn = 0; nn < 2; ++nn)
#pragma unroll
      for (int r = 0; r < 4; ++r) {
        float v = acc1[m][nn][r] + bv[nn];
        acc1[m][nn][r] = v > 0.f ? v : expm1f(v);
      }
  __syncthreads();  // all z reads complete; reuse sm as h1
#pragma unroll
  for (int m = 0; m < 4; ++m)
#pragma unroll
    for (int nn = 0; nn < 2; ++nn) {
      int c = (2 * wv + nn) * 16 + l15;
#pragma unroll
      for (int r = 0; r < 4; ++r)
        sm[(m * 16 + l4 * 4 + r) * PH1 + c] = f2h(acc1[m][nn][r]);
    }
  __syncthreads();
  // phase 3: gemm2 via MFMA. wave wv -> FOUT n-tile wv.
  h8 bf2[4];
#pragma unroll
  for (int kb = 0; kb < 4; ++kb)
    bf2[kb] = *(const h8*)&W2f[((((size_t)g * 4 + wv) * 4 + kb) * 64 + lane) * 8];
  int colo = wv * 16 + l15;
#pragma unroll
  for (int m = 0; m < 4; ++m) {
    f4 a2 = (f4){0.f, 0.f, 0.f, 0.f};
#pragma unroll
    for (int kb = 0; kb < 4; ++kb) {
      h8 af = *(const h8*)&sm[(m * 16 + l15) * PH1 + kb * 32 + l4 * 8];
      a2 = __builtin_amdgcn_mfma_f32_16x16x32_f16(af, bf2[kb], a2, 0, 0, 0);
    }
#pragma unroll
    for (int r = 0; r < 4; ++r) {
      int row = R0 + m * 16 + l4 * 4 + r;
      if (row < N) {
        float dd = dinv[g * N + row];
        H2s[((size_t)g * N + row) * FOUT + colo] = f2h(a2[r] * dd);
      }
    }
  }
}

// layer 2: out = ELU(dinv[d]*(sum h2s) + b); h2s pre-scaled by dinv[s]
template <int F>
__global__ __launch_bounds__(256) void k_agg_out(const ushort* __restrict__ Hsrc,
                                                 const int* __restrict__ rowptr,
                                                 const int* __restrict__ col,
                                                 const float* __restrict__ dinv,
                                                 const float* __restrict__ bias,
                                                 float* __restrict__ out) {
  int g, chunk;
  xcd_map(blockIdx.x, g, chunk);
  int d = __builtin_amdgcn_readfirstlane(chunk * 4 + (threadIdx.x >> 6));
  int lane = threadIdx.x & 63;
  const ushort* hb = Hsrc + (size_t)g * N * F;
  const int* cl = col + (size_t)g * E;
  int rs = rowptr[g * (N + 1) + d];
  int re = rowptr[g * (N + 1) + d + 1];
  float acc = h2f(hb[(size_t)d * F + lane]);  // self loop
  acc = agg_row(hb, cl, rs, re, lane, acc);
  float p = acc * dinv[g * N + d] + bias[g * F + lane];
  p = p > 0.f ? p : expm1f(p);
  out[((size_t)g * N + d) * F + lane] = p;
}

extern "C" void kernel_launch(void* const* d_in, const int* in_sizes, int n_in,
                              void* d_out, int out_size, void* d_ws, size_t ws_size,
                              hipStream_t stream) {
  const float* x = (const float*)d_in[0];
  const int* ei = (const int*)d_in[1];
  const float* W1 = (const float*)d_in[2];
  const float* b1 = (const float*)d_in[3];
  const float* W2 = (const float*)d_in[4];
  const float* b2 = (const float*)d_in[5];
  float* out = (float*)d_out;

  char* p = (char*)d_ws;
  auto alloc = [&](size_t bytes) {
    char* r = p;
    p += (bytes + 255) & ~(size_t)255;
    return r;
  };
  int* cnt = (int*)alloc(sizeof(int) * G * N);
  int* rowptr = (int*)alloc(sizeof(int) * G * (N + 1));
  int* part = (int*)alloc(sizeof(int) * G * NB);
  float* dinv = (float*)alloc(sizeof(float) * G * N);
  int* col = (int*)alloc(sizeof(int) * (size_t)G * E);             // 12.8 MB
  float* z = (float*)alloc(sizeof(float) * (size_t)G * N * FIN);   // 51.2 MB (h2s home)
  char* scratch = (char*)alloc((size_t)103 << 20);                 // radix + frag + xh
  ushort* h2s = (ushort*)z;  // fp16, 25.6 MB
  unsigned* pairs = (unsigned*)scratch;                    // 12.8 MB
  int* PH = (int*)(scratch + ((size_t)13 << 20));          // 200KB
  int* POFF = (int*)(scratch + ((size_t)14 << 20));        // 200KB
  int* BB = (int*)(scratch + ((size_t)15 << 20));          // 3.2KB
  ushort* W1f = (ushort*)(scratch + ((size_t)16 << 20));   // 64KB fp16 fragments
  ushort* W2f = (ushort*)(scratch + ((size_t)17 << 20));   // 64KB
  ushort* xh = (ushort*)(scratch + ((size_t)32 << 20));    // fp16 x, 25.6 MB

  // 0. W fragment prep (independent of CSR)
  k_wprep<<<G, 64, 0, stream>>>(W1, W2, W1f, W2f);

  // 1. CSR build via two-pass radix partition (line-contiguous writes only)
  k_phist<<<dim3(PB, G), 256, 0, stream>>>(ei, PH);
  k_pscan<<<G, 256, 0, stream>>>(PH, POFF, BB);
  k_part<<<dim3(PB, G), 256, 0, stream>>>(ei, POFF, pairs);
  k_bcnt<<<dim3(NBK, G), 256, 0, stream>>>(pairs, BB, cnt);
  dim3 sg(NB, G);
  k_scan_partial<<<sg, 256, 0, stream>>>(cnt, part);
  k_scan_mid<<<G, 64, 0, stream>>>(part, rowptr);
  k_scan_final<<<sg, 256, 0, stream>>>(cnt, part, rowptr, dinv);
  k_place<<<dim3(NBK, G), 256, 0, stream>>>(pairs, BB, rowptr, col);

  // 2. x -> fp16 pre-scaled by dinv
  k_x2h<<<(G * N * FIN / 4 + 255) / 256, 256, 0, stream>>>(
      (const float4*)x, dinv, (ushort4*)xh, G * N * FIN / 4);

  // 3. fused layer 1: aggregate (LDS z) -> MFMA gemm1 -> fp16 h1 (LDS) -> MFMA gemm2
  k_l1<<<8 * NTH, 256, 0, stream>>>(xh, rowptr, col, dinv, W1f, b1, W2f, h2s);

  // 4. layer 2 aggregate + bias + ELU
  k_agg_out<FOUT><<<(G * N) / 4, 256, 0, stream>>>(h2s, rowptr, col, dinv, b2, out);
}